// Round 12
// baseline (147.206 us; speedup 1.0000x reference)
//
#include <hip/hip_runtime.h>

#define DIM 256
#define NHEADS 8
#define HDIM 32

typedef _Float16 half8_t __attribute__((ext_vector_type(8)));
typedef _Float16 half4_t __attribute__((ext_vector_type(4)));
typedef float float4_t __attribute__((ext_vector_type(4)));

__device__ __forceinline__ void gload_lds16(const void* g, void* l) {
    __builtin_amdgcn_global_load_lds((const __attribute__((address_space(1))) void*)g,
                                     (__attribute__((address_space(3))) void*)l,
                                     16, 0, 0);
}

// scale * log2(e): exp(S*scale) == exp2(S') with Q pre-scaled by this.
#define QSCALE 0.25503093964976485f

// ---------------------------------------------------------------------------
// prep_w: Wqkv [256,768] -> WqT [768,256] fp16; Wout [256,256] -> WoT fp16.
// ---------------------------------------------------------------------------
__global__ __launch_bounds__(256) void prep_w(const float* __restrict__ Wqkv,
                                              const float* __restrict__ Wout,
                                              _Float16* __restrict__ WqT,
                                              _Float16* __restrict__ WoT) {
    __shared__ float ts[32][33];
    const int bid = blockIdx.x, t = threadIdx.x;
    const float* src; _Float16* dst; int N, kb, nb;
    if (bid < 192) { src = Wqkv; dst = WqT; N = 768; nb = bid % 24; kb = bid / 24; }
    else           { int b3 = bid - 192; src = Wout; dst = WoT; N = 256; nb = b3 % 8; kb = b3 / 8; }
    const int tx = t & 31, ty = t >> 5;
    #pragma unroll
    for (int i = 0; i < 4; ++i)
        ts[ty + i * 8][tx] = src[(size_t)(kb * 32 + ty + i * 8) * N + nb * 32 + tx];
    __syncthreads();
    #pragma unroll
    for (int i = 0; i < 4; ++i) {
        int nl = ty + i * 8;
        dst[(size_t)(nb * 32 + nl) * 256 + kb * 32 + tx] = (_Float16)ts[tx][nl];
    }
}

// ---------------------------------------------------------------------------
// qkv GEMM: C = x[8192,256](fp32, cvt in staging) @ WqT[768,256]^T.
// 64x64 tile, BK=32, 4 waves (32x32 each) -> 1536 blocks (6/CU) for latency
// hiding. Epilogue routes by n-range:
//   n<256   -> Q : qh[row][col] fp16, PRE-SCALED by QSCALE (for exp2)
//   256-511 -> K : kpack[bh][key][d]           (1KB contiguous per 16-key frag)
//   512-767 -> V : vp[bh][key/32][d][key%32]   (1KB contiguous per PV frag)
// ---------------------------------------------------------------------------
__global__ __launch_bounds__(256) void gemm_qkv(const float* __restrict__ x,
                                                const _Float16* __restrict__ BT,
                                                _Float16* __restrict__ qh,
                                                _Float16* __restrict__ kpack,
                                                _Float16* __restrict__ vp) {
    __shared__ alignas(16) _Float16 As[64 * 32];
    __shared__ alignas(16) _Float16 Bs[64 * 32];
    const int t = threadIdx.x, lane = t & 63, wave = t >> 6;
    const int l16 = lane & 15, quad = lane >> 4;
    const int m0 = blockIdx.y * 64, n0 = blockIdx.x * 64;
    const int wr = (wave >> 1) * 32, wc = (wave & 1) * 32;
    const int K = 256;

    float4_t acc[2][2];
    #pragma unroll
    for (int i = 0; i < 2; ++i)
        #pragma unroll
        for (int j = 0; j < 2; ++j) acc[i][j] = (float4_t){0.f, 0.f, 0.f, 0.f};

    const int arow = t >> 2;           // 0..63
    const int acol = (t & 3) * 8;      // halves
    const int srow = lane >> 2;        // 0..15
    const int scol = (lane & 3) * 8;

    for (int k0 = 0; k0 < K; k0 += 32) {
        {
            const float* xp = x + (size_t)(m0 + arow) * K + k0 + acol;
            float tmp[8];
            *reinterpret_cast<float4*>(tmp)     = *reinterpret_cast<const float4*>(xp);
            *reinterpret_cast<float4*>(tmp + 4) = *reinterpret_cast<const float4*>(xp + 4);
            half8_t h;
            #pragma unroll
            for (int j = 0; j < 8; ++j) h[j] = (_Float16)tmp[j];
            *reinterpret_cast<half8_t*>(As + arow * 32 + acol) = h;
        }
        // B: 4 chunks of 16 rows, wave w stages chunk w
        gload_lds16(BT + (size_t)(n0 + wave * 16 + srow) * K + k0 + scol, Bs + wave * 512);
        __syncthreads();
        half8_t af[2], bf[2];
        #pragma unroll
        for (int i = 0; i < 2; ++i)
            af[i] = *reinterpret_cast<const half8_t*>(As + (wr + i * 16 + l16) * 32 + quad * 8);
        #pragma unroll
        for (int j = 0; j < 2; ++j)
            bf[j] = *reinterpret_cast<const half8_t*>(Bs + (wc + j * 16 + l16) * 32 + quad * 8);
        #pragma unroll
        for (int i = 0; i < 2; ++i)
            #pragma unroll
            for (int j = 0; j < 2; ++j)
                acc[i][j] = __builtin_amdgcn_mfma_f32_16x16x32_f16(af[i], bf[j], acc[i][j], 0, 0, 0);
        __syncthreads();
    }

    const int bb = m0 >> 11;
    if (n0 < 256) {
        // Q: row-major, pre-scaled for exp2
        #pragma unroll
        for (int i = 0; i < 2; ++i)
            #pragma unroll
            for (int r = 0; r < 4; ++r) {
                int row = m0 + wr + i * 16 + quad * 4 + r;
                #pragma unroll
                for (int j = 0; j < 2; ++j)
                    qh[(size_t)row * 256 + n0 + wc + j * 16 + l16] =
                        (_Float16)(acc[i][j][r] * QSCALE);
            }
    } else if (n0 < 512) {
        // K: kpack[bh][tok][d]
        #pragma unroll
        for (int i = 0; i < 2; ++i)
            #pragma unroll
            for (int r = 0; r < 4; ++r) {
                int tok = (m0 & 2047) + wr + i * 16 + quad * 4 + r;
                #pragma unroll
                for (int j = 0; j < 2; ++j) {
                    int kc = n0 + wc + j * 16 + l16 - 256;
                    int hh = kc >> 5, dd = kc & 31;
                    kpack[((size_t)(bb * NHEADS + hh) * 2048 + tok) * 32 + dd] =
                        (_Float16)acc[i][j][r];
                }
            }
    } else {
        // V: vp[bh][chunk][d][tok%32], 4 tokens per half4 store
        #pragma unroll
        for (int i = 0; i < 2; ++i) {
            int tok0 = (m0 & 2047) + wr + i * 16 + quad * 4;
            int chunk = tok0 >> 5, tl = tok0 & 31;
            #pragma unroll
            for (int j = 0; j < 2; ++j) {
                int vc = n0 + wc + j * 16 + l16 - 512;
                int hh = vc >> 5, dd = vc & 31;
                half4_t p;
                #pragma unroll
                for (int r = 0; r < 4; ++r) p[r] = (_Float16)acc[i][j][r];
                *reinterpret_cast<half4_t*>(
                    vp + (((size_t)(bb * NHEADS + hh) * 64 + chunk) * 32 + dd) * 32 + tl) = p;
            }
        }
    }
}

// ---------------------------------------------------------------------------
// MFMA flash attention v11 = R8's v7 core (VALU denominator — accumulator
// registers for a ones-MFMA denom cost load-hoisting VGPRs and re-exposed
// global latency in v10) + exp2(prescaled Q) + per-head-contiguous NUM.
// 64 q/wave, kh x2, direct-global packed K/V reads, LDS only for the E
// round-trip. Grid: 512 = (b,h) x 8 qb(256) x 2 kh(1024).
// ---------------------------------------------------------------------------
__global__ __launch_bounds__(256, 2) void attn_v11(const _Float16* __restrict__ qh,
                                                   const _Float16* __restrict__ kpack,
                                                   const _Float16* __restrict__ vp,
                                                   _Float16* __restrict__ NUM,
                                                   float* __restrict__ DEN) {
    __shared__ alignas(16) _Float16 es[4][64][40];
    const int bid = blockIdx.x;
    const int kh = bid & 1;
    const int qb = (bid >> 1) & 7;
    const int bh = bid >> 4;
    const int b = bh >> 3;
    const int h = bh & 7;
    const int t = threadIdx.x, lane = t & 63, wave = t >> 6;
    const int l16 = lane & 15, quad = lane >> 4;
    const int bN = b * 2048;
    const int q0w = qb * 256 + wave * 64;
    const int kbeg = kh * 1024;

    // Q fragments (B-operand of S^T): 4 groups of 16 q (pre-scaled by QSCALE).
    half8_t qf[4];
    {
        const _Float16* qrow = qh + (size_t)(bN + q0w + l16) * 256 + h * HDIM + quad * 8;
        #pragma unroll
        for (int g = 0; g < 4; ++g)
            qf[g] = *reinterpret_cast<const half8_t*>(qrow + (size_t)g * 16 * 256);
    }

    const _Float16* kb_ = kpack + (size_t)bh * 65536;   // [2048][32]
    const _Float16* vb_ = vp + (size_t)bh * 65536;      // [64][32][32]

    float4_t num[4][2];
    #pragma unroll
    for (int g = 0; g < 4; ++g) {
        num[g][0] = (float4_t){0.f, 0.f, 0.f, 0.f};
        num[g][1] = (float4_t){0.f, 0.f, 0.f, 0.f};
    }
    float ds[4] = {0.f, 0.f, 0.f, 0.f};

    _Float16* esw = &es[wave][0][0];
    const float4_t z = {0.f, 0.f, 0.f, 0.f};

    for (int k0 = kbeg; k0 < kbeg + 1024; k0 += 64) {
        // K frags: 4 x 1KB contiguous; V frags: 2 chunks x 2 hd-halves x 1KB.
        half8_t kf[4], vf[4];
        #pragma unroll
        for (int j = 0; j < 4; ++j)
            kf[j] = *reinterpret_cast<const half8_t*>(
                kb_ + (size_t)(k0 + j * 16 + l16) * 32 + quad * 8);
        const int c0 = k0 >> 5;
        #pragma unroll
        for (int s = 0; s < 2; ++s)
            #pragma unroll
            for (int m = 0; m < 2; ++m)
                vf[s * 2 + m] = *reinterpret_cast<const half8_t*>(
                    vb_ + ((size_t)(c0 + s) * 32 + m * 16 + l16) * 32 + quad * 8);

        // S^T = K Q'^T : lane holds S^T[key=kb*16+quad*4+r][q=g*16+l16]
        float4_t st[4][4];
        #pragma unroll
        for (int kb = 0; kb < 4; ++kb)
            #pragma unroll
            for (int g = 0; g < 4; ++g)
                st[kb][g] = __builtin_amdgcn_mfma_f32_16x16x32_f16(kf[kb], qf[g], z, 0, 0, 0);

        // e = exp2(s'); accumulate denom in VALU; pack fp16 half4 per (kb,g).
        half4_t ep[4][4];
        #pragma unroll
        for (int kb = 0; kb < 4; ++kb)
            #pragma unroll
            for (int g = 0; g < 4; ++g)
                #pragma unroll
                for (int r = 0; r < 4; ++r) {
                    float e = __builtin_exp2f(st[kb][g][r]);
                    ds[g] += e;
                    ep[kb][g][r] = (_Float16)e;
                }

        // Two 32-key chunks: E -> LDS (b64), A-frags back (b128), PV MFMAs.
        #pragma unroll
        for (int s = 0; s < 2; ++s) {
            #pragma unroll
            for (int tt = 0; tt < 2; ++tt)
                #pragma unroll
                for (int g = 0; g < 4; ++g)
                    *reinterpret_cast<half4_t*>(
                        esw + (g * 16 + l16) * 40 + tt * 16 + quad * 4) = ep[s * 2 + tt][g];

            #pragma unroll
            for (int g = 0; g < 4; ++g) {
                half8_t ef = *reinterpret_cast<const half8_t*>(
                    esw + (g * 16 + l16) * 40 + quad * 8);
                num[g][0] = __builtin_amdgcn_mfma_f32_16x16x32_f16(ef, vf[s * 2],     num[g][0], 0, 0, 0);
                num[g][1] = __builtin_amdgcn_mfma_f32_16x16x32_f16(ef, vf[s * 2 + 1], num[g][1], 0, 0, 0);
            }
        }
    }

    // denom partials: sum the 4 key-quads per q column.
    #pragma unroll
    for (int g = 0; g < 4; ++g) {
        ds[g] += __shfl_xor(ds[g], 16, 64);
        ds[g] += __shfl_xor(ds[g], 32, 64);
    }

    // NUM: per-head-contiguous [kh][bh][tok][32] — block-private dense 16KB.
    _Float16* ob = NUM + (size_t)kh * 2097152 + ((size_t)bh * 2048 + q0w) * 32;
    #pragma unroll
    for (int g = 0; g < 4; ++g)
        #pragma unroll
        for (int r = 0; r < 4; ++r) {
            size_t ro = (size_t)(g * 16 + quad * 4 + r) * 32;
            ob[ro + l16]      = (_Float16)num[g][0][r];
            ob[ro + 16 + l16] = (_Float16)num[g][1][r];
        }
    if (quad == 0) {
        #pragma unroll
        for (int g = 0; g < 4; ++g)
            DEN[kh * 65536 + bh * 2048 + q0w + g * 16 + l16] = ds[g];
    }
}

// ---------------------------------------------------------------------------
// gemm2 + combine fused: out = [(N0+N1)*rcp(D0+D1+eps)] @ WoT^T + bout (fp32).
// 64m x 32n tile, BK=32, 4 waves (32x16 each) -> 1024 blocks (4/CU).
// A synthesized from per-head-contiguous NUM partials (dense gathers).
// ---------------------------------------------------------------------------
__global__ __launch_bounds__(256) void gemm2c(const _Float16* __restrict__ NUM,
                                              const float* __restrict__ DEN,
                                              const _Float16* __restrict__ BT,
                                              const float* __restrict__ bias,
                                              float* __restrict__ out) {
    __shared__ alignas(16) _Float16 As[64 * 32];
    __shared__ alignas(16) _Float16 Bs[32 * 32];
    const int t = threadIdx.x, lane = t & 63, wave = t >> 6;
    const int l16 = lane & 15, quad = lane >> 4;
    const int m0 = blockIdx.y * 64, n0 = blockIdx.x * 32;
    const int wr = (wave >> 1) * 32, wc = (wave & 1) * 16;
    const int bb = m0 >> 11;

    const int arow = t >> 2;            // 0..63
    const int acol = (t & 3) * 8;       // halves
    const int srow = lane >> 2;         // 0..15
    const int scol = (lane & 3) * 8;
    const int tok = (m0 + arow) & 2047;
    _Float16 rcp8[8];
    #pragma unroll
    for (int hh = 0; hh < 8; ++hh) {
        int di = (bb * 8 + hh) * 2048 + tok;
        rcp8[hh] = (_Float16)(1.f / (DEN[di] + DEN[di + 65536] + 1e-6f));
    }

    float4_t acc[2];
    acc[0] = (float4_t){0.f, 0.f, 0.f, 0.f};
    acc[1] = (float4_t){0.f, 0.f, 0.f, 0.f};

    for (int k0 = 0; k0 < 256; k0 += 32) {
        const int hh = k0 >> 5;
        const _Float16* np = NUM + (((size_t)(bb * 8 + hh) * 2048 + tok) * 32) + acol;
        half8_t s0 = *reinterpret_cast<const half8_t*>(np);
        half8_t s1 = *reinterpret_cast<const half8_t*>(np + 2097152);
        *reinterpret_cast<half8_t*>(As + arow * 32 + acol) = (s0 + s1) * rcp8[hh];
        if (wave < 2)
            gload_lds16(BT + (size_t)(n0 + wave * 16 + srow) * 256 + k0 + scol,
                        Bs + wave * 512);
        __syncthreads();
        half8_t af[2], bf;
        #pragma unroll
        for (int i = 0; i < 2; ++i)
            af[i] = *reinterpret_cast<const half8_t*>(As + (wr + i * 16 + l16) * 32 + quad * 8);
        bf = *reinterpret_cast<const half8_t*>(Bs + (wc + l16) * 32 + quad * 8);
        acc[0] = __builtin_amdgcn_mfma_f32_16x16x32_f16(af[0], bf, acc[0], 0, 0, 0);
        acc[1] = __builtin_amdgcn_mfma_f32_16x16x32_f16(af[1], bf, acc[1], 0, 0, 0);
        __syncthreads();
    }

    #pragma unroll
    for (int i = 0; i < 2; ++i)
        #pragma unroll
        for (int r = 0; r < 4; ++r) {
            int row = m0 + wr + i * 16 + quad * 4 + r;
            int col = n0 + wc + l16;
            out[(size_t)row * 256 + col] = acc[i][r] + bias[col];
        }
}

extern "C" void kernel_launch(void* const* d_in, const int* in_sizes, int n_in,
                              void* d_out, int out_size, void* d_ws, size_t ws_size,
                              hipStream_t stream) {
    const float* x    = (const float*)d_in[0];
    const float* Wqkv = (const float*)d_in[1];
    const float* Wout = (const float*)d_in[2];
    const float* bout = (const float*)d_in[3];
    float* out = (float*)d_out;
    const int M = 8192;

    _Float16* WqT   = (_Float16*)d_ws;                 // [768,256]
    _Float16* WoT   = WqT + 768 * 256;                 // [256,256]
    _Float16* qh    = WoT + 256 * 256;                 // [8192,256] (pre-scaled)
    _Float16* kpack = qh + (size_t)M * DIM;            // [32][2048][32]
    _Float16* vp    = kpack + (size_t)32 * 2048 * 32;  // [32][64][32][32]
    _Float16* NUM   = vp + (size_t)32 * 2048 * 32;     // [2][32][2048][32]
    float*    DEN   = (float*)(NUM + (size_t)2 * M * DIM);  // [2][65536]

    hipLaunchKernelGGL(prep_w, dim3(256), dim3(256), 0, stream, Wqkv, Wout, WqT, WoT);
    hipLaunchKernelGGL(gemm_qkv, dim3(12, 128), dim3(256), 0, stream, x, WqT, qh, kpack, vp);
    hipLaunchKernelGGL(attn_v11, dim3(512), dim3(256), 0, stream, qh, kpack, vp, NUM, DEN);
    hipLaunchKernelGGL(gemm2c, dim3(8, 128), dim3(256), 0, stream, NUM, DEN, WoT, bout, out);
}